// Round 7
// baseline (719.765 us; speedup 1.0000x reference)
//
#include <hip/hip_runtime.h>

#define CIN    32
#define COUT   32
#define KMAX   27
#define SCAN_B 2048

typedef _Float16 h2_t __attribute__((ext_vector_type(2)));

__device__ __forceinline__ float dot2(unsigned f, unsigned w, float a)
{
#if __has_builtin(__builtin_amdgcn_fdot2)
    return __builtin_amdgcn_fdot2(__builtin_bit_cast(h2_t, f),
                                  __builtin_bit_cast(h2_t, w), a, false);
#else
    h2_t ff = __builtin_bit_cast(h2_t, f), ww = __builtin_bit_cast(h2_t, w);
    return a + (float)ff.x * (float)ff.x * 0.f + (float)ff.x * (float)ww.x + (float)ff.y * (float)ww.y;
#endif
}

__device__ __forceinline__ unsigned f2h2(float a, float b)
{
    unsigned short ua = __builtin_bit_cast(unsigned short, (_Float16)a);
    unsigned short ub = __builtin_bit_cast(unsigned short, (_Float16)b);
    return (unsigned)ua | ((unsigned)ub << 16);
}

// ---- pack weights to f16 pairs: uint idx = ((k*4+j)*32 + o)*4 + dj holds
//      input channels (8j+2dj, 8j+2dj+1) for output channel o ----
__global__ void kb_pack(const float* __restrict__ w, unsigned* __restrict__ wH, int total)
{
    int idx = blockIdx.x * blockDim.x + threadIdx.x;
    if (idx >= total) return;
    int dj = idx & 3, o = (idx >> 2) & 31, j = (idx >> 7) & 3, k = idx >> 9;
    int i0 = 8 * j + 2 * dj;
    wH[idx] = f2h2(w[(k * CIN + i0) * COUT + o], w[(k * CIN + i0 + 1) * COUT + o]);
}

// ---- pack features: float4 -> uint2 of f16 pairs; idx over N*8 ----
__global__ void kf_pack(const float* __restrict__ f, unsigned* __restrict__ fH, int total4)
{
    int idx = blockIdx.x * blockDim.x + threadIdx.x;
    if (idx >= total4) return;
    float4 v = ((const float4*)f)[idx];
    uint2 r; r.x = f2h2(v.x, v.y); r.y = f2h2(v.z, v.w);
    ((uint2*)fH)[idx] = r;
}

// ---- per-row k-mask, 4 pairs/thread (injective within k => 1 bit/(row,k)) ----
__global__ void kb_mask(const int* __restrict__ scatter, unsigned* __restrict__ mask,
                        int npair, int M, int vec_ok)
{
    int k = blockIdx.y;
    const int* sp = scatter + (size_t)k * npair;
    int t = blockIdx.x * blockDim.x + threadIdx.x;
    if (vec_ok) {
        int base = t * 4;
        if (base >= npair) return;
        unsigned kb = 1u << k;
        if (base + 3 < npair) {
            int4 s4 = *(const int4*)(sp + base);
            if (s4.x < M) atomicOr(&mask[s4.x], kb);
            if (s4.y < M) atomicOr(&mask[s4.y], kb);
            if (s4.z < M) atomicOr(&mask[s4.z], kb);
            if (s4.w < M) atomicOr(&mask[s4.w], kb);
        } else {
            for (int p = base; p < npair; ++p) {
                int s = sp[p];
                if (s < M) atomicOr(&mask[s], kb);
            }
        }
    } else {
        if (t >= npair) return;
        int s = sp[t];
        if (s < M) atomicOr(&mask[s], 1u << k);
    }
}

// ---- scan level 1: per-block sums of popcount(mask) ----
__global__ void kb_scan1(const unsigned* __restrict__ mask, int* __restrict__ part, int n)
{
    __shared__ int red[256];
    int base = blockIdx.x * SCAN_B;
    int sum = 0;
    for (int i = threadIdx.x; i < SCAN_B; i += 256) {
        int idx = base + i;
        sum += (idx < n) ? __popc(mask[idx]) : 0;
    }
    red[threadIdx.x] = sum;
    __syncthreads();
    for (int s = 128; s > 0; s >>= 1) {
        if (threadIdx.x < s) red[threadIdx.x] += red[threadIdx.x + s];
        __syncthreads();
    }
    if (threadIdx.x == 0) part[blockIdx.x] = red[0];
}

// ---- scan level 2: single-block exclusive scan of part[0..nb), nb<=2048 ----
__global__ void kb_scan2(int* __restrict__ part, int nb, int* __restrict__ total_out)
{
    __shared__ int a[2048], b[2048];
    int t = threadIdx.x;
    for (int i = t; i < 2048; i += 1024) a[i] = (i < nb) ? part[i] : 0;
    __syncthreads();
    int* src = a; int* dst = b;
    for (int ofs = 1; ofs < 2048; ofs <<= 1) {
        for (int i = t; i < 2048; i += 1024)
            dst[i] = (i >= ofs) ? src[i] + src[i - ofs] : src[i];
        __syncthreads();
        int* tmp = src; src = dst; dst = tmp;
    }
    for (int i = t; i < 2048; i += 1024)
        if (i < nb) part[i] = (i == 0) ? 0 : src[i - 1];
    if (t == 0) *total_out = src[nb - 1];
}

// ---- scan level 3: block-local exclusive scan of popcounts + block offset ----
__global__ void kb_scan3(const unsigned* __restrict__ mask, const int* __restrict__ part,
                         int* __restrict__ row_start, int n)
{
    __shared__ int ts[256];
    int base = blockIdx.x * SCAN_B;
    int v[8];
    int sum = 0;
#pragma unroll
    for (int j = 0; j < 8; ++j) {
        int idx = base + threadIdx.x * 8 + j;
        v[j] = (idx < n) ? __popc(mask[idx]) : 0;
        sum += v[j];
    }
    ts[threadIdx.x] = sum;
    __syncthreads();
    for (int ofs = 1; ofs < 256; ofs <<= 1) {
        int add = (threadIdx.x >= ofs) ? ts[threadIdx.x - ofs] : 0;
        __syncthreads();
        ts[threadIdx.x] += add;
        __syncthreads();
    }
    int excl = (threadIdx.x == 0) ? 0 : ts[threadIdx.x - 1];
    excl += part[blockIdx.x];
#pragma unroll
    for (int j = 0; j < 8; ++j) {
        int idx = base + threadIdx.x * 8 + j;
        if (idx < n) row_start[idx] = excl;
        excl += v[j];
    }
}

// ---- build CSR entries, 4 pairs/thread; slot deterministic (k-ascending) ----
__global__ void kb_build(const int* __restrict__ gather, const int* __restrict__ scatter,
                         const unsigned* __restrict__ mask, const int* __restrict__ row_start,
                         int* __restrict__ list, int npair, int M, int vec_ok)
{
    int k = blockIdx.y;
    const int* sp = scatter + (size_t)k * npair;
    const int* gp = gather  + (size_t)k * npair;
    unsigned klow = (1u << k) - 1u;
    int t = blockIdx.x * blockDim.x + threadIdx.x;
    if (vec_ok) {
        int base = t * 4;
        if (base >= npair) return;
        if (base + 3 < npair) {
            int4 s4 = *(const int4*)(sp + base);
            int4 g4 = *(const int4*)(gp + base);
            if (s4.x < M) list[row_start[s4.x] + __popc(mask[s4.x] & klow)] = (k << 18) | g4.x;
            if (s4.y < M) list[row_start[s4.y] + __popc(mask[s4.y] & klow)] = (k << 18) | g4.y;
            if (s4.z < M) list[row_start[s4.z] + __popc(mask[s4.z] & klow)] = (k << 18) | g4.z;
            if (s4.w < M) list[row_start[s4.w] + __popc(mask[s4.w] & klow)] = (k << 18) | g4.w;
        } else {
            for (int p = base; p < npair; ++p) {
                int s = sp[p];
                if (s < M) list[row_start[s] + __popc(mask[s] & klow)] = (k << 18) | gp[p];
            }
        }
    } else {
        if (t >= npair) return;
        int s = sp[t];
        if (s < M) list[row_start[s] + __popc(mask[s] & klow)] = (k << 18) | gp[t];
    }
}

// ---- per-entry accumulate: 4 uint4 feat (uniform/broadcast), 4 LDS b128, 16 dot2 ----
__device__ __forceinline__ void entry_accum(int pk, int lane, const uint4* __restrict__ wL,
                                            const uint4* __restrict__ featH,
                                            float& a0, float& a1, float& a2, float& a3)
{
    int k = pk >> 18, g = pk & 0x3FFFF;
    const uint4* fr = featH + ((size_t)g << 2);
    uint4 f0 = fr[0], f1 = fr[1], f2 = fr[2], f3 = fr[3];
    const uint4* wr = wL + k * 128 + lane;
    uint4 w0 = wr[0], w1 = wr[32], w2 = wr[64], w3 = wr[96];
    a0 = dot2(f0.x, w0.x, a0); a0 = dot2(f0.y, w0.y, a0);
    a0 = dot2(f0.z, w0.z, a0); a0 = dot2(f0.w, w0.w, a0);
    a1 = dot2(f1.x, w1.x, a1); a1 = dot2(f1.y, w1.y, a1);
    a1 = dot2(f1.z, w1.z, a1); a1 = dot2(f1.w, w1.w, a1);
    a2 = dot2(f2.x, w2.x, a2); a2 = dot2(f2.y, w2.y, a2);
    a2 = dot2(f2.z, w2.z, a2); a2 = dot2(f2.w, w2.w, a2);
    a3 = dot2(f3.x, w3.x, a3); a3 = dot2(f3.y, w3.y, a3);
    a3 = dot2(f3.z, w3.z, a3); a3 = dot2(f3.w, w3.w, a3);
}

// ---- main: 2 rows per half-wave per iter, first 2 entries prefetched ----
__global__ __launch_bounds__(1024)
void kb_main(const uint4* __restrict__ featH, const uint4* __restrict__ wH,
             const int* __restrict__ row_start, const int* __restrict__ list,
             float* __restrict__ out, int M, int K)
{
    __shared__ uint4 wL[KMAX * 128];                 // 55296 B
    for (int i = threadIdx.x; i < K * 128; i += 1024) wL[i] = wH[i];
    __syncthreads();

    const int lane = threadIdx.x & 31;               // output channel
    int h  = (blockIdx.x * 1024 + threadIdx.x) >> 5;
    int nh = (gridDim.x * 1024) >> 5;

    for (int mA = h; mA < M; mA += 2 * nh) {
        const int mB = mA + nh;
        const bool hasB = (mB < M);
        // issue all row-bound loads first (independent)
        int eA0 = row_start[mA], eA1 = row_start[mA + 1];
        int eB0 = 0, eB1 = 0;
        if (hasB) { eB0 = row_start[mB]; eB1 = row_start[mB + 1]; }
        // prefetch up to 2 list entries per row (independent streams)
        const int cA = eA1 - eA0, cB = eB1 - eB0;
        int pkA0 = 0, pkA1 = 0, pkB0 = 0, pkB1 = 0;
        if (cA > 0) pkA0 = list[eA0];
        if (hasB && cB > 0) pkB0 = list[eB0];
        if (cA > 1) pkA1 = list[eA0 + 1];
        if (hasB && cB > 1) pkB1 = list[eB0 + 1];

        float aA0 = 0.f, aA1 = 0.f, aA2 = 0.f, aA3 = 0.f;
        float aB0 = 0.f, aB1 = 0.f, aB2 = 0.f, aB3 = 0.f;

        if (cA > 0) entry_accum(pkA0, lane, wL, featH, aA0, aA1, aA2, aA3);
        if (hasB && cB > 0) entry_accum(pkB0, lane, wL, featH, aB0, aB1, aB2, aB3);
        if (cA > 1) entry_accum(pkA1, lane, wL, featH, aA0, aA1, aA2, aA3);
        if (hasB && cB > 1) entry_accum(pkB1, lane, wL, featH, aB0, aB1, aB2, aB3);
        for (int e = eA0 + 2; e < eA1; ++e)
            entry_accum(list[e], lane, wL, featH, aA0, aA1, aA2, aA3);
        if (hasB)
            for (int e = eB0 + 2; e < eB1; ++e)
                entry_accum(list[e], lane, wL, featH, aB0, aB1, aB2, aB3);

        out[(size_t)mA * COUT + lane] = (aA0 + aA1) + (aA2 + aA3);
        if (hasB) out[(size_t)mB * COUT + lane] = (aB0 + aB1) + (aB2 + aB3);
    }
}

// ---- fallback (R1): atomic scatter ----
__global__ __launch_bounds__(256, 4)
void spconv_scatter(const float* __restrict__ feat, const float* __restrict__ weight,
                    const int* __restrict__ gather, const int* __restrict__ scatter,
                    float* __restrict__ out, int npair, int M)
{
    const int k = blockIdx.y;
    const int lane = threadIdx.x & 31;
    const int sub = threadIdx.x >> 5;
    const int pairs_per_blk = blockDim.x >> 5;
    const float* wk = weight + (size_t)k * (CIN * COUT);
    float w[CIN];
#pragma unroll
    for (int i = 0; i < CIN; ++i) w[i] = wk[i * COUT + lane];
    const int* gk = gather + (size_t)k * npair;
    const int* sk = scatter + (size_t)k * npair;
    for (int p = blockIdx.x * pairs_per_blk + sub; p < npair; p += gridDim.x * pairs_per_blk) {
        int s = sk[p];
        if (s >= M) continue;
        int g = gk[p];
        const float4* fr = (const float4*)(feat + (size_t)g * CIN);
        float a = 0.f;
#pragma unroll
        for (int c = 0; c < 8; ++c) {
            float4 f4 = fr[c];
            a = fmaf(f4.x, w[4*c+0], a); a = fmaf(f4.y, w[4*c+1], a);
            a = fmaf(f4.z, w[4*c+2], a); a = fmaf(f4.w, w[4*c+3], a);
        }
        atomicAdd(&out[(size_t)s * COUT + lane], a);
    }
}

extern "C" void kernel_launch(void* const* d_in, const int* in_sizes, int n_in,
                              void* d_out, int out_size, void* d_ws, size_t ws_size,
                              hipStream_t stream)
{
    const float* feat    = (const float*)d_in[0];
    const float* weight  = (const float*)d_in[1];
    const int*   gather  = (const int*)d_in[2];
    const int*   scatter = (const int*)d_in[3];
    float*       out     = (float*)d_out;

    const int N     = in_sizes[0] / CIN;            // 150000 input sites
    const int K     = in_sizes[1] / (CIN * COUT);   // 27
    const int npair = in_sizes[2] / K;              // 150000
    const int M     = out_size / COUT;              // num_out (~2.13M)
    const int NB    = (M + SCAN_B - 1) / SCAN_B;    // scan blocks (~1041)

    // workspace layout
    uintptr_t base = (uintptr_t)d_ws;
    auto align16 = [](uintptr_t p) { return (p + 15) & ~(uintptr_t)15; };
    uintptr_t p_mask = align16(base);                              // M uints
    uintptr_t p_rs   = align16(p_mask + (size_t)M * 4);            // M+1 ints
    uintptr_t p_part = align16(p_rs + ((size_t)M + 1) * 4);        // 2048 ints
    uintptr_t p_wH   = align16(p_part + 2048 * 4);                 // K*512 uints
    uintptr_t p_fH   = align16(p_wH + (size_t)K * 512 * 4);        // N*16 uints
    uintptr_t p_list = align16(p_fH + (size_t)N * 16 * 4);         // K*npair ints
    uintptr_t p_end  = p_list + (size_t)K * npair * 4;

    if (p_end - base > ws_size || NB > 2048 || K > KMAX) {
        hipMemsetAsync(d_out, 0, (size_t)out_size * sizeof(float), stream);
        dim3 grid(160, K);
        spconv_scatter<<<grid, 256, 0, stream>>>(feat, weight, gather, scatter, out, npair, M);
        return;
    }

    unsigned* mask      = (unsigned*)p_mask;
    int*      row_start = (int*)p_rs;
    int*      part      = (int*)p_part;
    unsigned* wH        = (unsigned*)p_wH;
    unsigned* fH        = (unsigned*)p_fH;
    int*      list      = (int*)p_list;

    const int vec_ok = ((npair & 3) == 0) ? 1 : 0;

    hipMemsetAsync(mask, 0, (size_t)M * 4, stream);

    kb_pack<<<(K * 512 + 255) / 256, 256, 0, stream>>>(weight, wH, K * 512);
    kf_pack<<<(N * 8 + 255) / 256, 256, 0, stream>>>(feat, fH, N * 8);

    const int pthreads = vec_ok ? (npair + 3) / 4 : npair;
    dim3 gp((pthreads + 255) / 256, K);
    kb_mask<<<gp, 256, 0, stream>>>(scatter, mask, npair, M, vec_ok);

    kb_scan1<<<NB, 256, 0, stream>>>(mask, part, M);
    kb_scan2<<<1, 1024, 0, stream>>>(part, NB, row_start + M);   // also writes total
    kb_scan3<<<NB, 256, 0, stream>>>(mask, part, row_start, M);

    kb_build<<<gp, 256, 0, stream>>>(gather, scatter, mask, row_start, list, npair, M, vec_ok);

    // write-once main: every output row covered, no memset of d_out
    kb_main<<<512, 1024, 0, stream>>>((const uint4*)fH, (const uint4*)wH,
                                      row_start, list, out, M, K);
}

// Round 8
// 716.051 us; speedup vs baseline: 1.0052x; 1.0052x over previous
//
#include <hip/hip_runtime.h>

#define CIN    32
#define COUT   32
#define KMAX   27
#define SCAN_B 2048
#define GB     512          // fused grid blocks (must be <= co-resident capacity)
#define BT     1024         // fused block threads
#define GSZ    (GB * BT)

typedef _Float16 h2_t __attribute__((ext_vector_type(2)));

__device__ __forceinline__ float dot2(unsigned f, unsigned w, float a)
{
#if __has_builtin(__builtin_amdgcn_fdot2)
    return __builtin_amdgcn_fdot2(__builtin_bit_cast(h2_t, f),
                                  __builtin_bit_cast(h2_t, w), a, false);
#else
    h2_t ff = __builtin_bit_cast(h2_t, f), ww = __builtin_bit_cast(h2_t, w);
    return a + (float)ff.x * (float)ww.x + (float)ff.y * (float)ww.y;
#endif
}

__device__ __forceinline__ unsigned f2h2(float a, float b)
{
    unsigned short ua = __builtin_bit_cast(unsigned short, (_Float16)a);
    unsigned short ub = __builtin_bit_cast(unsigned short, (_Float16)b);
    return (unsigned)ua | ((unsigned)ub << 16);
}

// device-scope grid barrier: all GB blocks co-resident (verified host-side)
__device__ __forceinline__ void gsync(int* bar, int target)
{
    __syncthreads();
    if (threadIdx.x == 0) {
        __threadfence();   // publish this block's writes (agent scope)
        __hip_atomic_fetch_add(bar, 1, __ATOMIC_RELEASE, __HIP_MEMORY_SCOPE_AGENT);
        while (__hip_atomic_load(bar, __ATOMIC_ACQUIRE, __HIP_MEMORY_SCOPE_AGENT) < target)
            __builtin_amdgcn_s_sleep(8);
    }
    __syncthreads();
}

// ---- per-entry accumulate: 4 uint4 feat (uniform/broadcast), 4 LDS b128, 16 dot2 ----
__device__ __forceinline__ void entry_accum(int pk, int lane, const uint4* __restrict__ wL,
                                            const uint4* __restrict__ featH,
                                            float& a0, float& a1, float& a2, float& a3)
{
    int k = pk >> 18, g = pk & 0x3FFFF;
    const uint4* fr = featH + ((size_t)g << 2);
    uint4 f0 = fr[0], f1 = fr[1], f2 = fr[2], f3 = fr[3];
    const uint4* wr = wL + k * 128 + lane;
    uint4 w0 = wr[0], w1 = wr[32], w2 = wr[64], w3 = wr[96];
    a0 = dot2(f0.x, w0.x, a0); a0 = dot2(f0.y, w0.y, a0);
    a0 = dot2(f0.z, w0.z, a0); a0 = dot2(f0.w, w0.w, a0);
    a1 = dot2(f1.x, w1.x, a1); a1 = dot2(f1.y, w1.y, a1);
    a1 = dot2(f1.z, w1.z, a1); a1 = dot2(f1.w, w1.w, a1);
    a2 = dot2(f2.x, w2.x, a2); a2 = dot2(f2.y, w2.y, a2);
    a2 = dot2(f2.z, w2.z, a2); a2 = dot2(f2.w, w2.w, a2);
    a3 = dot2(f3.x, w3.x, a3); a3 = dot2(f3.y, w3.y, a3);
    a3 = dot2(f3.z, w3.z, a3); a3 = dot2(f3.w, w3.w, a3);
}

// =================== FUSED persistent kernel ===================
__global__ __launch_bounds__(BT, 8)
void kb_fused(const float* __restrict__ feat, const float* __restrict__ weight,
              const int* __restrict__ gather, const int* __restrict__ scatter,
              unsigned* __restrict__ mask, int* __restrict__ row_start,
              int* __restrict__ part, unsigned* __restrict__ wH,
              unsigned* __restrict__ fH, int* __restrict__ list,
              int* __restrict__ bar, float* __restrict__ out,
              int N, int npair, int M, int K, int vec_ok)
{
    __shared__ uint4 wL[KMAX * 128];        // 55296 B (main phase)
    __shared__ int sA[BT], sB[BT];          // 8192 B (scan phases)
    const int tid  = threadIdx.x;
    const int gtid = blockIdx.x * BT + tid;
    const int rng  = (M + GB - 1) / GB;     // rows per block for scan phases

    // ---- P0: zero mask; pack weights -> wH (f16 pairs); pack feat -> fH ----
    for (int i = gtid; i < M; i += GSZ) mask[i] = 0u;
    for (int i = gtid; i < K * 512; i += GSZ) {
        int dj = i & 3, o = (i >> 2) & 31, j = (i >> 7) & 3, k = i >> 9;
        int i0 = 8 * j + 2 * dj;
        wH[i] = f2h2(weight[(k * CIN + i0) * COUT + o],
                     weight[(k * CIN + i0 + 1) * COUT + o]);
    }
    for (int i = gtid; i < N * 8; i += GSZ) {
        float4 v = ((const float4*)feat)[i];
        uint2 r; r.x = f2h2(v.x, v.y); r.y = f2h2(v.z, v.w);
        ((uint2*)fH)[i] = r;
    }
    gsync(bar, GB * 1);

    // ---- P1: per-row k-mask (injective within k => 1 bit per (row,k)) ----
    if (vec_ok) {
        const int npair4 = npair >> 2;
        const int tot = K * npair4;
        for (int t = gtid; t < tot; t += GSZ) {
            int k = t / npair4, i = t - k * npair4;
            unsigned kb = 1u << k;
            int4 s4 = *(const int4*)(scatter + (size_t)k * npair + i * 4);
            if (s4.x < M) atomicOr(&mask[s4.x], kb);
            if (s4.y < M) atomicOr(&mask[s4.y], kb);
            if (s4.z < M) atomicOr(&mask[s4.z], kb);
            if (s4.w < M) atomicOr(&mask[s4.w], kb);
        }
    } else {
        const int tot = K * npair;
        for (int t = gtid; t < tot; t += GSZ) {
            int k = t / npair, i = t - k * npair;
            int s = scatter[(size_t)k * npair + i];
            if (s < M) atomicOr(&mask[s], 1u << k);
        }
    }
    gsync(bar, GB * 2);

    // ---- P2: per-block popcount sums ----
    {
        int lo = blockIdx.x * rng, hi = lo + rng;
        if (hi > M) hi = M;
        int sum = 0;
        for (int i = lo + tid; i < hi; i += BT) sum += __popc(mask[i]);
        sA[tid] = sum; __syncthreads();
        for (int s = 512; s > 0; s >>= 1) {
            if (tid < s) sA[tid] += sA[tid + s];
            __syncthreads();
        }
        if (tid == 0) part[blockIdx.x] = sA[0];
    }
    gsync(bar, GB * 3);

    // ---- P3: block 0 exclusive-scans part[0..GB) ----
    if (blockIdx.x == 0) {
        sA[tid] = (tid < GB) ? part[tid] : 0;
        __syncthreads();
        int* src = sA; int* dst = sB;
        for (int ofs = 1; ofs < BT; ofs <<= 1) {
            dst[tid] = (tid >= ofs) ? src[tid] + src[tid - ofs] : src[tid];
            __syncthreads();
            int* tmp = src; src = dst; dst = tmp;
        }
        if (tid < GB) part[tid] = (tid == 0) ? 0 : src[tid - 1];
        if (tid == 0) row_start[M] = src[GB - 1];   // grand total
    }
    gsync(bar, GB * 4);

    // ---- P4: per-block local exclusive scan + block offset -> row_start ----
    {
        int lo = blockIdx.x * rng, hi = lo + rng;
        if (hi > M) hi = M;
        const int per = (rng + BT - 1) / BT;        // <= 8 (host-checked)
        int base = lo + tid * per;
        int cnt[8];
        int sum = 0;
#pragma unroll
        for (int j = 0; j < 8; ++j) {
            int idx = base + j;
            int ok = (j < per) && (idx < hi);
            cnt[j] = ok ? __popc(mask[idx]) : 0;
            sum += cnt[j];
        }
        sA[tid] = sum; __syncthreads();
        int* src = sA; int* dst = sB;
        for (int ofs = 1; ofs < BT; ofs <<= 1) {
            dst[tid] = (tid >= ofs) ? src[tid] + src[tid - ofs] : src[tid];
            __syncthreads();
            int* tmp = src; src = dst; dst = tmp;
        }
        int excl = (tid == 0) ? 0 : src[tid - 1];
        excl += part[blockIdx.x];
#pragma unroll
        for (int j = 0; j < 8; ++j) {
            int idx = base + j;
            if (j < per && idx < hi) row_start[idx] = excl;
            excl += cnt[j];
        }
    }
    gsync(bar, GB * 5);

    // ---- P5: build CSR entries (slot = row_start[s] + popc(mask below k)) ----
    if (vec_ok) {
        const int npair4 = npair >> 2;
        const int tot = K * npair4;
        for (int t = gtid; t < tot; t += GSZ) {
            int k = t / npair4, i = t - k * npair4;
            unsigned klow = (1u << k) - 1u;
            int4 s4 = *(const int4*)(scatter + (size_t)k * npair + i * 4);
            int4 g4 = *(const int4*)(gather  + (size_t)k * npair + i * 4);
            if (s4.x < M) list[row_start[s4.x] + __popc(mask[s4.x] & klow)] = (k << 18) | g4.x;
            if (s4.y < M) list[row_start[s4.y] + __popc(mask[s4.y] & klow)] = (k << 18) | g4.y;
            if (s4.z < M) list[row_start[s4.z] + __popc(mask[s4.z] & klow)] = (k << 18) | g4.z;
            if (s4.w < M) list[row_start[s4.w] + __popc(mask[s4.w] & klow)] = (k << 18) | g4.w;
        }
    } else {
        const int tot = K * npair;
        for (int t = gtid; t < tot; t += GSZ) {
            int k = t / npair, i = t - k * npair;
            unsigned klow = (1u << k) - 1u;
            int s = scatter[(size_t)k * npair + i];
            if (s < M) list[row_start[s] + __popc(mask[s] & klow)] =
                           (k << 18) | gather[(size_t)k * npair + i];
        }
    }
    gsync(bar, GB * 6);

    // ---- P6: main (weights in LDS, f16 dot2, half-wave per row, write-once) ----
    for (int i = tid; i < K * 128; i += BT) wL[i] = ((const uint4*)wH)[i];
    __syncthreads();
    {
        const int lane = tid & 31;
        const int h  = gtid >> 5;
        const int nh = GSZ >> 5;
        const uint4* featH = (const uint4*)fH;
        for (int m = h; m < M; m += nh) {
            int e0 = row_start[m], e1 = row_start[m + 1];
            float a0 = 0.f, a1 = 0.f, a2 = 0.f, a3 = 0.f;
            for (int e = e0; e < e1; ++e)
                entry_accum(list[e], lane, wL, featH, a0, a1, a2, a3);
            out[(size_t)m * COUT + lane] = (a0 + a1) + (a2 + a3);
        }
    }
}

// =================== fallback path (proven R7 kernels) ===================
__global__ void kb_pack(const float* __restrict__ w, unsigned* __restrict__ wH, int total)
{
    int idx = blockIdx.x * blockDim.x + threadIdx.x;
    if (idx >= total) return;
    int dj = idx & 3, o = (idx >> 2) & 31, j = (idx >> 7) & 3, k = idx >> 9;
    int i0 = 8 * j + 2 * dj;
    wH[idx] = f2h2(w[(k * CIN + i0) * COUT + o], w[(k * CIN + i0 + 1) * COUT + o]);
}

__global__ void kf_pack(const float* __restrict__ f, unsigned* __restrict__ fH, int total4)
{
    int idx = blockIdx.x * blockDim.x + threadIdx.x;
    if (idx >= total4) return;
    float4 v = ((const float4*)f)[idx];
    uint2 r; r.x = f2h2(v.x, v.y); r.y = f2h2(v.z, v.w);
    ((uint2*)fH)[idx] = r;
}

__global__ void kb_mask(const int* __restrict__ scatter, unsigned* __restrict__ mask,
                        int npair, int M, int vec_ok)
{
    int k = blockIdx.y;
    const int* sp = scatter + (size_t)k * npair;
    int t = blockIdx.x * blockDim.x + threadIdx.x;
    if (vec_ok) {
        int base = t * 4;
        if (base >= npair) return;
        unsigned kb = 1u << k;
        if (base + 3 < npair) {
            int4 s4 = *(const int4*)(sp + base);
            if (s4.x < M) atomicOr(&mask[s4.x], kb);
            if (s4.y < M) atomicOr(&mask[s4.y], kb);
            if (s4.z < M) atomicOr(&mask[s4.z], kb);
            if (s4.w < M) atomicOr(&mask[s4.w], kb);
        } else {
            for (int p = base; p < npair; ++p) {
                int s = sp[p];
                if (s < M) atomicOr(&mask[s], kb);
            }
        }
    } else {
        if (t >= npair) return;
        int s = sp[t];
        if (s < M) atomicOr(&mask[s], 1u << k);
    }
}

__global__ void kb_scan1(const unsigned* __restrict__ mask, int* __restrict__ part, int n)
{
    __shared__ int red[256];
    int base = blockIdx.x * SCAN_B;
    int sum = 0;
    for (int i = threadIdx.x; i < SCAN_B; i += 256) {
        int idx = base + i;
        sum += (idx < n) ? __popc(mask[idx]) : 0;
    }
    red[threadIdx.x] = sum;
    __syncthreads();
    for (int s = 128; s > 0; s >>= 1) {
        if (threadIdx.x < s) red[threadIdx.x] += red[threadIdx.x + s];
        __syncthreads();
    }
    if (threadIdx.x == 0) part[blockIdx.x] = red[0];
}

__global__ void kb_scan2(int* __restrict__ part, int nb, int* __restrict__ total_out)
{
    __shared__ int a[2048], b[2048];
    int t = threadIdx.x;
    for (int i = t; i < 2048; i += 1024) a[i] = (i < nb) ? part[i] : 0;
    __syncthreads();
    int* src = a; int* dst = b;
    for (int ofs = 1; ofs < 2048; ofs <<= 1) {
        for (int i = t; i < 2048; i += 1024)
            dst[i] = (i >= ofs) ? src[i] + src[i - ofs] : src[i];
        __syncthreads();
        int* tmp = src; src = dst; dst = tmp;
    }
    for (int i = t; i < 2048; i += 1024)
        if (i < nb) part[i] = (i == 0) ? 0 : src[i - 1];
    if (t == 0) *total_out = src[nb - 1];
}

__global__ void kb_scan3(const unsigned* __restrict__ mask, const int* __restrict__ part,
                         int* __restrict__ row_start, int n)
{
    __shared__ int ts[256];
    int base = blockIdx.x * SCAN_B;
    int v[8];
    int sum = 0;
#pragma unroll
    for (int j = 0; j < 8; ++j) {
        int idx = base + threadIdx.x * 8 + j;
        v[j] = (idx < n) ? __popc(mask[idx]) : 0;
        sum += v[j];
    }
    ts[threadIdx.x] = sum;
    __syncthreads();
    for (int ofs = 1; ofs < 256; ofs <<= 1) {
        int add = (threadIdx.x >= ofs) ? ts[threadIdx.x - ofs] : 0;
        __syncthreads();
        ts[threadIdx.x] += add;
        __syncthreads();
    }
    int excl = (threadIdx.x == 0) ? 0 : ts[threadIdx.x - 1];
    excl += part[blockIdx.x];
#pragma unroll
    for (int j = 0; j < 8; ++j) {
        int idx = base + threadIdx.x * 8 + j;
        if (idx < n) row_start[idx] = excl;
        excl += v[j];
    }
}

__global__ void kb_build(const int* __restrict__ gather, const int* __restrict__ scatter,
                         const unsigned* __restrict__ mask, const int* __restrict__ row_start,
                         int* __restrict__ list, int npair, int M, int vec_ok)
{
    int k = blockIdx.y;
    const int* sp = scatter + (size_t)k * npair;
    const int* gp = gather  + (size_t)k * npair;
    unsigned klow = (1u << k) - 1u;
    int t = blockIdx.x * blockDim.x + threadIdx.x;
    if (vec_ok) {
        int base = t * 4;
        if (base >= npair) return;
        if (base + 3 < npair) {
            int4 s4 = *(const int4*)(sp + base);
            int4 g4 = *(const int4*)(gp + base);
            if (s4.x < M) list[row_start[s4.x] + __popc(mask[s4.x] & klow)] = (k << 18) | g4.x;
            if (s4.y < M) list[row_start[s4.y] + __popc(mask[s4.y] & klow)] = (k << 18) | g4.y;
            if (s4.z < M) list[row_start[s4.z] + __popc(mask[s4.z] & klow)] = (k << 18) | g4.z;
            if (s4.w < M) list[row_start[s4.w] + __popc(mask[s4.w] & klow)] = (k << 18) | g4.w;
        } else {
            for (int p = base; p < npair; ++p) {
                int s = sp[p];
                if (s < M) list[row_start[s] + __popc(mask[s] & klow)] = (k << 18) | gp[p];
            }
        }
    } else {
        if (t >= npair) return;
        int s = sp[t];
        if (s < M) list[row_start[s] + __popc(mask[s] & klow)] = (k << 18) | gp[t];
    }
}

__global__ __launch_bounds__(1024)
void kb_main(const uint4* __restrict__ featH, const uint4* __restrict__ wH,
             const int* __restrict__ row_start, const int* __restrict__ list,
             float* __restrict__ out, int M, int K)
{
    __shared__ uint4 wL[KMAX * 128];
    for (int i = threadIdx.x; i < K * 128; i += 1024) wL[i] = wH[i];
    __syncthreads();
    const int lane = threadIdx.x & 31;
    int h  = (blockIdx.x * 1024 + threadIdx.x) >> 5;
    int nh = (gridDim.x * 1024) >> 5;
    for (int m = h; m < M; m += nh) {
        int e0 = row_start[m], e1 = row_start[m + 1];
        float a0 = 0.f, a1 = 0.f, a2 = 0.f, a3 = 0.f;
        for (int e = e0; e < e1; ++e)
            entry_accum(list[e], lane, wL, featH, a0, a1, a2, a3);
        out[(size_t)m * COUT + lane] = (a0 + a1) + (a2 + a3);
    }
}

__global__ __launch_bounds__(256, 4)
void spconv_scatter(const float* __restrict__ feat, const float* __restrict__ weight,
                    const int* __restrict__ gather, const int* __restrict__ scatter,
                    float* __restrict__ out, int npair, int M)
{
    const int k = blockIdx.y;
    const int lane = threadIdx.x & 31;
    const int sub = threadIdx.x >> 5;
    const int pairs_per_blk = blockDim.x >> 5;
    const float* wk = weight + (size_t)k * (CIN * COUT);
    float w[CIN];
#pragma unroll
    for (int i = 0; i < CIN; ++i) w[i] = wk[i * COUT + lane];
    const int* gk = gather + (size_t)k * npair;
    const int* sk = scatter + (size_t)k * npair;
    for (int p = blockIdx.x * pairs_per_blk + sub; p < npair; p += gridDim.x * pairs_per_blk) {
        int s = sk[p];
        if (s >= M) continue;
        int g = gk[p];
        const float4* fr = (const float4*)(feat + (size_t)g * CIN);
        float a = 0.f;
#pragma unroll
        for (int c = 0; c < 8; ++c) {
            float4 f4 = fr[c];
            a = fmaf(f4.x, w[4*c+0], a); a = fmaf(f4.y, w[4*c+1], a);
            a = fmaf(f4.z, w[4*c+2], a); a = fmaf(f4.w, w[4*c+3], a);
        }
        atomicAdd(&out[(size_t)s * COUT + lane], a);
    }
}

extern "C" void kernel_launch(void* const* d_in, const int* in_sizes, int n_in,
                              void* d_out, int out_size, void* d_ws, size_t ws_size,
                              hipStream_t stream)
{
    const float* feat    = (const float*)d_in[0];
    const float* weight  = (const float*)d_in[1];
    const int*   gather  = (const int*)d_in[2];
    const int*   scatter = (const int*)d_in[3];
    float*       out     = (float*)d_out;

    const int N     = in_sizes[0] / CIN;            // input sites
    const int K     = in_sizes[1] / (CIN * COUT);   // 27
    const int npair = in_sizes[2] / K;              // 150000
    const int M     = out_size / COUT;              // num_out (~2.13M)
    const int NB    = (M + SCAN_B - 1) / SCAN_B;

    // workspace layout: bar | mask | row_start | part | wH | fH | list
    uintptr_t base = (uintptr_t)d_ws;
    auto align16 = [](uintptr_t p) { return (p + 15) & ~(uintptr_t)15; };
    uintptr_t p_bar  = align16(base);                              // 16 ints
    uintptr_t p_mask = align16(p_bar + 64);                        // M uints
    uintptr_t p_rs   = align16(p_mask + (size_t)M * 4);            // M+1 ints
    uintptr_t p_part = align16(p_rs + ((size_t)M + 1) * 4);        // max(2048,GB) ints
    uintptr_t p_wH   = align16(p_part + 2048 * 4);                 // K*512 uints
    uintptr_t p_fH   = align16(p_wH + (size_t)K * 512 * 4);        // N*16 uints
    uintptr_t p_list = align16(p_fH + (size_t)N * 16 * 4);         // K*npair ints
    uintptr_t p_end  = p_list + (size_t)K * npair * 4;

    if (p_end - base > ws_size || K > KMAX) {
        hipMemsetAsync(d_out, 0, (size_t)out_size * sizeof(float), stream);
        dim3 grid(160, K);
        spconv_scatter<<<grid, 256, 0, stream>>>(feat, weight, gather, scatter, out, npair, M);
        return;
    }

    int*      bar       = (int*)p_bar;
    unsigned* mask      = (unsigned*)p_mask;
    int*      row_start = (int*)p_rs;
    int*      part      = (int*)p_part;
    unsigned* wH        = (unsigned*)p_wH;
    unsigned* fH        = (unsigned*)p_fH;
    int*      list      = (int*)p_list;

    const int vec_ok = ((npair & 3) == 0) ? 1 : 0;

    // ---- try fused persistent path: requires all GB blocks co-resident ----
    const int rng = (M + GB - 1) / GB;
    bool fused_ok = ((rng + BT - 1) / BT) <= 8;     // P4 per-thread chunk fits cnt[8]
    if (fused_ok) {
        int maxb = 0;
        hipError_t err = hipOccupancyMaxActiveBlocksPerMultiprocessor(
                             &maxb, (const void*)kb_fused, BT, 0);
        fused_ok = (err == hipSuccess) && (maxb >= 2);   // 2 blocks/CU x 256 CU >= GB
    }

    if (fused_ok) {
        hipMemsetAsync(bar, 0, 64, stream);
        kb_fused<<<GB, BT, 0, stream>>>(feat, weight, gather, scatter,
                                        mask, row_start, part, wH, fH, list,
                                        bar, out, N, npair, M, K, vec_ok);
        return;
    }

    // ---- fallback: proven R7 multi-kernel path ----
    if (NB > 2048) {
        hipMemsetAsync(d_out, 0, (size_t)out_size * sizeof(float), stream);
        dim3 grid(160, K);
        spconv_scatter<<<grid, 256, 0, stream>>>(feat, weight, gather, scatter, out, npair, M);
        return;
    }

    hipMemsetAsync(mask, 0, (size_t)M * 4, stream);
    kb_pack<<<(K * 512 + 255) / 256, 256, 0, stream>>>(weight, wH, K * 512);
    kf_pack<<<(N * 8 + 255) / 256, 256, 0, stream>>>(feat, fH, N * 8);

    const int pthreads = vec_ok ? (npair + 3) / 4 : npair;
    dim3 gp((pthreads + 255) / 256, K);
    kb_mask<<<gp, 256, 0, stream>>>(scatter, mask, npair, M, vec_ok);

    kb_scan1<<<NB, 256, 0, stream>>>(mask, part, M);
    kb_scan2<<<1, 1024, 0, stream>>>(part, NB, row_start + M);
    kb_scan3<<<NB, 256, 0, stream>>>(mask, part, row_start, M);

    kb_build<<<gp, 256, 0, stream>>>(gather, scatter, mask, row_start, list, npair, M, vec_ok);

    kb_main<<<512, 1024, 0, stream>>>((const uint4*)fH, (const uint4*)wH,
                                      row_start, list, out, M, K);
}